// Round 2
// baseline (507.343 us; speedup 1.0000x reference)
//
#include <hip/hip_runtime.h>
#include <stdint.h>

// B=4, T=2048, C=1024, H=16, HD=64
// qkv buffer: [B*T][3C] bf16 ; att buffer: [B*T][C] bf16

typedef float f32x4 __attribute__((ext_vector_type(4)));
typedef short s16x8 __attribute__((ext_vector_type(8)));

typedef __attribute__((address_space(1))) const unsigned int gu32;
typedef __attribute__((address_space(3))) unsigned int lu32;

__device__ __forceinline__ unsigned short f2b(float f) {
  unsigned u = __builtin_bit_cast(unsigned, f);
  u += 0x7fffu + ((u >> 16) & 1u);
  return (unsigned short)(u >> 16);
}

__device__ __forceinline__ void gload16(const void* g, void* l) {
  __builtin_amdgcn_global_load_lds((gu32*)g, (lu32*)l, 16, 0, 0);
}

// ---------------- fp32 -> bf16 conversion ----------------
__global__ __launch_bounds__(256) void cvt_kernel(const float* __restrict__ in,
                                                  unsigned short* __restrict__ out,
                                                  int n4) {
  int i = blockIdx.x * 256 + threadIdx.x;
  if (i < n4) {
    float4 v = reinterpret_cast<const float4*>(in)[i];
    ushort4 o;
    o.x = f2b(v.x); o.y = f2b(v.y); o.z = f2b(v.z); o.w = f2b(v.w);
    reinterpret_cast<ushort4*>(out)[i] = o;
  }
}

// ---------------- GEMM: C[M][N] = A[M][K] * B[N][K]^T (+bias) ----------------
// 128x128 tile, BK=64, 4 waves (2x2), each wave 64x64 (4x4 frags of 16x16).
template <int M, int N, int K, bool BIAS, bool OUTF32>
__global__ __launch_bounds__(256) void gemm_bt(const unsigned short* __restrict__ A,
                                               const unsigned short* __restrict__ B,
                                               const float* __restrict__ bias,
                                               void* __restrict__ C) {
  __shared__ __align__(16) unsigned short As[128 * 64];
  __shared__ __align__(16) unsigned short Bs[128 * 64];
  const int tid = threadIdx.x;
  const int l = tid & 63, w = tid >> 6;
  const int l15 = l & 15, lq = l >> 4;
  const int wr = w >> 1, wc = w & 1;
  const int m0 = blockIdx.y * 128, n0 = blockIdx.x * 128;
  f32x4 acc[4][4] = {};
  for (int k0 = 0; k0 < K; k0 += 64) {
    __syncthreads();
#pragma unroll
    for (int i = 0; i < 4; i++) {
      int idx = i * 256 + tid;
      gload16(A + (size_t)(m0 + (idx >> 3)) * K + k0 + (idx & 7) * 8, &As[idx * 8]);
    }
#pragma unroll
    for (int i = 0; i < 4; i++) {
      int idx = i * 256 + tid;
      gload16(B + (size_t)(n0 + (idx >> 3)) * K + k0 + (idx & 7) * 8, &Bs[idx * 8]);
    }
    __syncthreads();
#pragma unroll
    for (int kk = 0; kk < 2; kk++) {
      s16x8 af[4], bfv[4];
#pragma unroll
      for (int m = 0; m < 4; m++)
        af[m] = *(const s16x8*)&As[(wr * 64 + m * 16 + l15) * 64 + kk * 32 + lq * 8];
#pragma unroll
      for (int n = 0; n < 4; n++)
        bfv[n] = *(const s16x8*)&Bs[(wc * 64 + n * 16 + l15) * 64 + kk * 32 + lq * 8];
#pragma unroll
      for (int m = 0; m < 4; m++)
#pragma unroll
        for (int n = 0; n < 4; n++)
          acc[m][n] = __builtin_amdgcn_mfma_f32_16x16x32_bf16(af[m], bfv[n], acc[m][n], 0, 0, 0);
    }
  }
#pragma unroll
  for (int m = 0; m < 4; m++)
#pragma unroll
    for (int n = 0; n < 4; n++)
#pragma unroll
      for (int r = 0; r < 4; r++) {
        int row = m0 + wr * 64 + m * 16 + lq * 4 + r;
        int col = n0 + wc * 64 + n * 16 + l15;
        float v = acc[m][n][r];
        if (BIAS) v += bias[col];
        if (OUTF32)
          ((float*)C)[(size_t)row * N + col] = v;
        else
          ((unsigned short*)C)[(size_t)row * N + col] = f2b(v);
      }
}

// ---------------- Flash attention (causal) ----------------
// 1 block = (b, h, 64 q rows); 4 waves x 16 q rows each; KV tiles of 64.
__global__ __launch_bounds__(256) void attn_kernel(const unsigned short* __restrict__ qkv,
                                                   unsigned short* __restrict__ attb) {
  __shared__ __align__(16) unsigned short Ks[64 * 64];  // [key][d]
  __shared__ __align__(16) unsigned short Vt[64 * 64];  // [d][key]
  __shared__ __align__(16) unsigned short Pl[4][16 * 64];  // per-wave P scratch
  const int tid = threadIdx.x, l = tid & 63, w = tid >> 6;
  const int l15 = l & 15, lq = l >> 4;
  const int bid = blockIdx.x;
  const int qblk = bid & 31, h = (bid >> 5) & 15, b = bid >> 9;
  const int q0 = qblk * 64;
  const unsigned short* base = qkv + (size_t)b * 2048 * 3072;

  // Q fragments in registers (A-operand layout): row = l&15, k = kk*32 + lq*8 + j
  s16x8 qf[2];
  {
    int qrow = q0 + w * 16 + l15;
#pragma unroll
    for (int kk = 0; kk < 2; kk++)
      qf[kk] = *(const s16x8*)&base[(size_t)qrow * 3072 + h * 64 + kk * 32 + lq * 8];
  }
  f32x4 oacc[4] = {};
  float mrow[4] = {-1e30f, -1e30f, -1e30f, -1e30f};
  float lrow[4] = {0.f, 0.f, 0.f, 0.f};

  const int nt = qblk + 1;
  for (int t = 0; t < nt; ++t) {
    const int kv0 = t * 64;
    __syncthreads();
    // stage K tile [64][64] via global_load_lds (linear)
#pragma unroll
    for (int i = 0; i < 2; i++) {
      int idx = i * 256 + tid;
      gload16(base + (size_t)(kv0 + (idx >> 3)) * 3072 + 1024 + h * 64 + (idx & 7) * 8,
              &Ks[idx * 8]);
    }
    // stage V^T tile [d][key] via registers (coalesced read, scattered ds_write)
#pragma unroll
    for (int i = 0; i < 2; i++) {
      int vr = (tid >> 3) + i * 32, c8 = (tid & 7) * 8;
      s16x8 vv = *(const s16x8*)&base[(size_t)(kv0 + vr) * 3072 + 2048 + h * 64 + c8];
#pragma unroll
      for (int j = 0; j < 8; j++) Vt[(c8 + j) * 64 + vr] = (unsigned short)vv[j];
    }
    __syncthreads();

    // S = Q K^T  (16 x 64 per wave)
    f32x4 s[4];
#pragma unroll
    for (int n = 0; n < 4; n++) s[n] = (f32x4){0.f, 0.f, 0.f, 0.f};
#pragma unroll
    for (int kk = 0; kk < 2; kk++) {
#pragma unroll
      for (int n = 0; n < 4; n++) {
        s16x8 bk = *(const s16x8*)&Ks[(n * 16 + l15) * 64 + kk * 32 + lq * 8];
        s[n] = __builtin_amdgcn_mfma_f32_16x16x32_bf16(qf[kk], bk, s[n], 0, 0, 0);
      }
    }

    // scale, causal mask, online softmax
#pragma unroll
    for (int r = 0; r < 4; r++) {
      const int qg = q0 + w * 16 + lq * 4 + r;
      float mx = -1e30f;
#pragma unroll
      for (int n = 0; n < 4; n++) {
        int kg = kv0 + n * 16 + l15;
        float v = (kg <= qg) ? s[n][r] * 0.125f : -1e30f;
        s[n][r] = v;
        mx = fmaxf(mx, v);
      }
      mx = fmaxf(mx, __shfl_xor(mx, 1));
      mx = fmaxf(mx, __shfl_xor(mx, 2));
      mx = fmaxf(mx, __shfl_xor(mx, 4));
      mx = fmaxf(mx, __shfl_xor(mx, 8));
      float mn = fmaxf(mrow[r], mx);
      float alpha = exp2f((mrow[r] - mn) * 1.44269504f);
      mrow[r] = mn;
      float ssum = 0.f;
#pragma unroll
      for (int n = 0; n < 4; n++) {
        float p = exp2f((s[n][r] - mn) * 1.44269504f);
        s[n][r] = p;
        ssum += p;
      }
      ssum += __shfl_xor(ssum, 1);
      ssum += __shfl_xor(ssum, 2);
      ssum += __shfl_xor(ssum, 4);
      ssum += __shfl_xor(ssum, 8);
      lrow[r] = lrow[r] * alpha + ssum;
#pragma unroll
      for (int d = 0; d < 4; d++) oacc[d][r] *= alpha;
    }

    // P (C-layout f32) -> LDS bf16 (A-layout source)
#pragma unroll
    for (int r = 0; r < 4; r++)
#pragma unroll
      for (int n = 0; n < 4; n++)
        Pl[w][(lq * 4 + r) * 64 + n * 16 + l15] = f2b(s[n][r]);

    // O += P V
    s16x8 ap[2];
#pragma unroll
    for (int kk = 0; kk < 2; kk++)
      ap[kk] = *(const s16x8*)&Pl[w][l15 * 64 + kk * 32 + lq * 8];
#pragma unroll
    for (int d = 0; d < 4; d++) {
#pragma unroll
      for (int kk = 0; kk < 2; kk++) {
        s16x8 bv = *(const s16x8*)&Vt[(d * 16 + l15) * 64 + kk * 32 + lq * 8];
        oacc[d] = __builtin_amdgcn_mfma_f32_16x16x32_bf16(ap[kk], bv, oacc[d], 0, 0, 0);
      }
    }
  }

  // normalize + store att output [B*T][C] bf16
#pragma unroll
  for (int d = 0; d < 4; d++)
#pragma unroll
    for (int r = 0; r < 4; r++) {
      int qg = q0 + w * 16 + lq * 4 + r;
      int col = h * 64 + d * 16 + l15;
      float v = oacc[d][r] / lrow[r];
      attb[((size_t)b * 2048 + qg) * 1024 + col] = f2b(v);
    }
}

extern "C" void kernel_launch(void* const* d_in, const int* in_sizes, int n_in,
                              void* d_out, int out_size, void* d_ws, size_t ws_size,
                              hipStream_t stream) {
  const float* x = (const float*)d_in[0];      // [4,2048,1024]
  const float* wqkv = (const float*)d_in[1];   // [3072,1024]
  const float* wproj = (const float*)d_in[2];  // [1024,1024]
  const float* bproj = (const float*)d_in[3];  // [1024]
  float* out = (float*)d_out;

  unsigned short* xb = (unsigned short*)d_ws;            // 8192*1024
  unsigned short* wqkvb = xb + (size_t)8192 * 1024;      // 3072*1024
  unsigned short* wprojb = wqkvb + (size_t)3072 * 1024;  // 1024*1024
  unsigned short* qkvb = wprojb + (size_t)1024 * 1024;   // 8192*3072
  unsigned short* attb = qkvb + (size_t)8192 * 3072;     // 8192*1024

  cvt_kernel<<<(8192 * 1024 / 4 + 255) / 256, 256, 0, stream>>>(x, xb, 8192 * 1024 / 4);
  cvt_kernel<<<(3072 * 1024 / 4 + 255) / 256, 256, 0, stream>>>(wqkv, wqkvb, 3072 * 1024 / 4);
  cvt_kernel<<<(1024 * 1024 / 4 + 255) / 256, 256, 0, stream>>>(wproj, wprojb, 1024 * 1024 / 4);

  gemm_bt<8192, 3072, 1024, false, false>
      <<<dim3(3072 / 128, 8192 / 128), 256, 0, stream>>>(xb, wqkvb, nullptr, qkvb);

  attn_kernel<<<4 * 16 * 32, 256, 0, stream>>>(qkvb, attb);

  gemm_bt<8192, 1024, 1024, true, true>
      <<<dim3(1024 / 128, 8192 / 128), 256, 0, stream>>>(attb, wprojb, bproj, out);
}

// Round 4
// 397.320 us; speedup vs baseline: 1.2769x; 1.2769x over previous
//
#include <hip/hip_runtime.h>
#include <stdint.h>

// B=4, T=2048, C=1024, H=16, HD=64
// qkb: [B*T][2048] bf16 (Q cols 0..1023, K cols 1024..2047)
// vt : [B][H][64][2048] bf16 (V transposed per head)
// attb: [B*T][1024] bf16

typedef float f32x4 __attribute__((ext_vector_type(4)));
typedef short s16x8 __attribute__((ext_vector_type(8)));
typedef unsigned short u16x4 __attribute__((ext_vector_type(4)));

typedef __attribute__((address_space(1))) const unsigned int gu32;
typedef __attribute__((address_space(3))) unsigned int lu32;

__device__ __forceinline__ unsigned short f2b(float f) {
  unsigned u = __builtin_bit_cast(unsigned, f);
  u += 0x7fffu + ((u >> 16) & 1u);
  return (unsigned short)(u >> 16);
}

__device__ __forceinline__ void gload16(const void* g, void* l) {
  __builtin_amdgcn_global_load_lds((gu32*)g, (lu32*)l, 16, 0, 0);
}

// ---------------- fp32 -> bf16 conversion ----------------
__global__ __launch_bounds__(256) void cvt_kernel(const float* __restrict__ in,
                                                  unsigned short* __restrict__ out,
                                                  int n4) {
  int i = blockIdx.x * 256 + threadIdx.x;
  if (i < n4) {
    float4 v = reinterpret_cast<const float4*>(in)[i];
    ushort4 o;
    o.x = f2b(v.x); o.y = f2b(v.y); o.z = f2b(v.z); o.w = f2b(v.w);
    reinterpret_cast<ushort4*>(out)[i] = o;
  }
}

// ---------------- GEMM: C = A[M][K] * B[N][K]^T ----------------
// OUTMODE 0: bf16 [M][N] -> C0
// OUTMODE 1: QKV split: cols<2048 -> qkb (C0, [M][2048]); cols>=2048 -> vt (C1, [B][H][64][2048])
// OUTMODE 2: f32 + bias -> C0
template <int M, int N, int K, int OUTMODE>
__global__ __launch_bounds__(256) void gemm_bt(const unsigned short* __restrict__ A,
                                               const unsigned short* __restrict__ B,
                                               const float* __restrict__ bias,
                                               void* __restrict__ C0,
                                               void* __restrict__ C1) {
  __shared__ __align__(16) unsigned short As[128 * 64];
  __shared__ __align__(16) unsigned short Bs[128 * 64];
  const int tid = threadIdx.x;
  const int l = tid & 63, w = tid >> 6;
  const int l15 = l & 15, lq = l >> 4;
  const int wr = w >> 1, wc = w & 1;
  const int m0 = blockIdx.y * 128, n0 = blockIdx.x * 128;
  f32x4 acc[4][4] = {};
  for (int k0 = 0; k0 < K; k0 += 64) {
    __syncthreads();
#pragma unroll
    for (int i = 0; i < 4; i++) {
      int idx = i * 256 + tid;
      gload16(A + (size_t)(m0 + (idx >> 3)) * K + k0 + (idx & 7) * 8, &As[idx * 8]);
    }
#pragma unroll
    for (int i = 0; i < 4; i++) {
      int idx = i * 256 + tid;
      gload16(B + (size_t)(n0 + (idx >> 3)) * K + k0 + (idx & 7) * 8, &Bs[idx * 8]);
    }
    __syncthreads();
#pragma unroll
    for (int kk = 0; kk < 2; kk++) {
      s16x8 af[4], bfv[4];
#pragma unroll
      for (int m = 0; m < 4; m++)
        af[m] = *(const s16x8*)&As[(wr * 64 + m * 16 + l15) * 64 + kk * 32 + lq * 8];
#pragma unroll
      for (int n = 0; n < 4; n++)
        bfv[n] = *(const s16x8*)&Bs[(wc * 64 + n * 16 + l15) * 64 + kk * 32 + lq * 8];
#pragma unroll
      for (int m = 0; m < 4; m++)
#pragma unroll
        for (int n = 0; n < 4; n++)
          acc[m][n] = __builtin_amdgcn_mfma_f32_16x16x32_bf16(af[m], bfv[n], acc[m][n], 0, 0, 0);
    }
  }
  if (OUTMODE == 1 && n0 >= 2048) {
    // V columns: write transposed into vt[b][h][d][q], pack 4 q (r=0..3) per store
    unsigned short* vt = (unsigned short*)C1;
#pragma unroll
    for (int m = 0; m < 4; m++)
#pragma unroll
      for (int n = 0; n < 4; n++) {
        int row0 = m0 + wr * 64 + m * 16 + lq * 4;  // q base (mult of 4)
        int vcol = n0 - 2048 + wc * 64 + n * 16 + l15;  // h*64+d
        int bb = row0 >> 11, q = row0 & 2047;
        u16x4 o;
#pragma unroll
        for (int r = 0; r < 4; r++) o[r] = f2b(acc[m][n][r]);
        *(u16x4*)&vt[((size_t)(bb * 16 + (vcol >> 6)) * 64 + (vcol & 63)) * 2048 + q] = o;
      }
  } else {
#pragma unroll
    for (int m = 0; m < 4; m++)
#pragma unroll
      for (int n = 0; n < 4; n++)
#pragma unroll
        for (int r = 0; r < 4; r++) {
          int row = m0 + wr * 64 + m * 16 + lq * 4 + r;
          int col = n0 + wc * 64 + n * 16 + l15;
          float v = acc[m][n][r];
          if (OUTMODE == 2) {
            ((float*)C0)[(size_t)row * N + col] = v + bias[col];
          } else if (OUTMODE == 1) {
            ((unsigned short*)C0)[(size_t)row * 2048 + col] = f2b(v);
          } else {
            ((unsigned short*)C0)[(size_t)row * N + col] = f2b(v);
          }
        }
  }
}

// ---------------- Flash attention (causal) ----------------
// 1 block = (b, h, 128 q rows); 4 waves x 32 q rows; KV tiles of 64, double-buffered.
// LDS tiles [64][64] bf16, 128-B rows, XOR-swizzled: byte ^= ((row&7)<<4).
__global__ __launch_bounds__(256) void attn_kernel(const unsigned short* __restrict__ qkb,
                                                   const unsigned short* __restrict__ vt,
                                                   unsigned short* __restrict__ attb) {
  __shared__ __align__(16) unsigned short Kb[2][64 * 64];
  __shared__ __align__(16) unsigned short Vb[2][64 * 64];
  __shared__ __align__(16) unsigned short Pl[4][32 * 64];
  const int tid = threadIdx.x, l = tid & 63, w = tid >> 6;
  const int l15 = l & 15, lq = l >> 4;
  const int bid = blockIdx.x;
  const int qb = 15 - (bid & 15);  // descending: long blocks first
  const int h = (bid >> 4) & 15, b = bid >> 8;
  const int q0 = qb * 128;
  const size_t rowbase = (size_t)b * 2048;
  const unsigned short* kbase = qkb + rowbase * 2048 + 1024 + h * 64;
  const unsigned short* vbase = vt + (size_t)(b * 16 + h) * 64 * 2048;
  const int swz = (l15 & 7) << 4;  // read-side XOR (byte units)

  // Q fragments in registers: qf[m][kk], row = q0+w*32+m*16+l15, k = kk*32+lq*8+j
  s16x8 qf[2][2];
#pragma unroll
  for (int m = 0; m < 2; m++)
#pragma unroll
    for (int kk = 0; kk < 2; kk++)
      qf[m][kk] = *(const s16x8*)&qkb[(rowbase + q0 + w * 32 + m * 16 + l15) * 2048 +
                                      h * 64 + kk * 32 + lq * 8];

  f32x4 oacc[2][4] = {};
  float mrow[2][4], lrow[2][4];
#pragma unroll
  for (int m = 0; m < 2; m++)
#pragma unroll
    for (int r = 0; r < 4; r++) { mrow[m][r] = -1e30f; lrow[m][r] = 0.f; }

  const int nt = (q0 >> 6) + 2;

  auto stage = [&](int bs, int t) {
    const int kv0 = t << 6;
#pragma unroll
    for (int i = 0; i < 2; i++) {
      int idx = i * 256 + tid;
      int row = idx >> 3, colb = (idx & 7) << 4;
      int src = colb ^ ((row & 7) << 4);
      gload16(kbase + (size_t)(kv0 + row) * 2048 + (src >> 1), &Kb[bs][idx * 8]);
    }
#pragma unroll
    for (int i = 0; i < 2; i++) {
      int idx = i * 256 + tid;
      int row = idx >> 3, colb = (idx & 7) << 4;
      int src = colb ^ ((row & 7) << 4);
      gload16(vbase + (size_t)row * 2048 + kv0 + (src >> 1), &Vb[bs][idx * 8]);
    }
  };

  stage(0, 0);
  __syncthreads();
  int cur = 0;
  for (int t = 0; t < nt; ++t) {
    const int kv0 = t << 6;
    if (t + 1 < nt) stage(cur ^ 1, t + 1);
    const int qwmin = q0 + w * 32;
    if (kv0 <= qwmin + 31) {  // wave has at least one unmasked row
      // ---- S = Q K^T (32 x 64 per wave) ----
      f32x4 s[2][4];
#pragma unroll
      for (int m = 0; m < 2; m++)
#pragma unroll
        for (int n = 0; n < 4; n++) s[m][n] = (f32x4){0.f, 0.f, 0.f, 0.f};
#pragma unroll
      for (int kk = 0; kk < 2; kk++) {
        s16x8 bk[4];
#pragma unroll
        for (int n = 0; n < 4; n++)
          bk[n] = *(const s16x8*)&Kb[cur][(n * 16 + l15) * 64 +
                                          (((kk * 64 + lq * 16) ^ swz) >> 1)];
#pragma unroll
        for (int m = 0; m < 2; m++)
#pragma unroll
          for (int n = 0; n < 4; n++)
            s[m][n] = __builtin_amdgcn_mfma_f32_16x16x32_bf16(qf[m][kk], bk[n], s[m][n], 0, 0, 0);
      }
      // ---- scale, mask, online softmax ----
      const bool needmask = (kv0 + 63) > qwmin;
#pragma unroll
      for (int m = 0; m < 2; m++)
#pragma unroll
        for (int r = 0; r < 4; r++) {
          const int qg = qwmin + m * 16 + lq * 4 + r;
          float mx = -1e30f;
#pragma unroll
          for (int n = 0; n < 4; n++) {
            float v = s[m][n][r] * 0.125f;
            if (needmask) v = (kv0 + n * 16 + l15 <= qg) ? v : -1e30f;
            s[m][n][r] = v;
            mx = fmaxf(mx, v);
          }
          mx = fmaxf(mx, __shfl_xor(mx, 1));
          mx = fmaxf(mx, __shfl_xor(mx, 2));
          mx = fmaxf(mx, __shfl_xor(mx, 4));
          mx = fmaxf(mx, __shfl_xor(mx, 8));
          float mn = fmaxf(mrow[m][r], mx);
          float alpha = exp2f((mrow[m][r] - mn) * 1.44269504f);
          mrow[m][r] = mn;
          float ssum = 0.f;
#pragma unroll
          for (int n = 0; n < 4; n++) {
            float p = exp2f((s[m][n][r] - mn) * 1.44269504f);
            s[m][n][r] = p;
            ssum += p;
          }
          ssum += __shfl_xor(ssum, 1);
          ssum += __shfl_xor(ssum, 2);
          ssum += __shfl_xor(ssum, 4);
          ssum += __shfl_xor(ssum, 8);
          lrow[m][r] = lrow[m][r] * alpha + ssum;
#pragma unroll
          for (int d = 0; d < 4; d++) oacc[m][d][r] *= alpha;
        }
      // ---- P -> LDS bf16 (swizzled) ----
#pragma unroll
      for (int m = 0; m < 2; m++)
#pragma unroll
        for (int r = 0; r < 4; r++) {
          int row = m * 16 + lq * 4 + r;
          int rx = (row & 7) << 4;
#pragma unroll
          for (int n = 0; n < 4; n++)
            Pl[w][row * 64 + ((((n * 16 + l15) * 2) ^ rx) >> 1)] = f2b(s[m][n][r]);
        }
      // ---- O += P V ----
      s16x8 ap[2][2];
#pragma unroll
      for (int m = 0; m < 2; m++)
#pragma unroll
        for (int kk = 0; kk < 2; kk++)
          ap[m][kk] = *(const s16x8*)&Pl[w][(m * 16 + l15) * 64 +
                                            (((kk * 64 + lq * 16) ^ swz) >> 1)];
#pragma unroll
      for (int kk = 0; kk < 2; kk++) {
        s16x8 bv[4];
#pragma unroll
        for (int d = 0; d < 4; d++)
          bv[d] = *(const s16x8*)&Vb[cur][(d * 16 + l15) * 64 +
                                          (((kk * 64 + lq * 16) ^ swz) >> 1)];
#pragma unroll
        for (int m = 0; m < 2; m++)
#pragma unroll
          for (int d = 0; d < 4; d++)
            oacc[m][d] = __builtin_amdgcn_mfma_f32_16x16x32_bf16(ap[m][kk], bv[d], oacc[m][d], 0, 0, 0);
      }
    }
    __syncthreads();
    cur ^= 1;
  }

  // ---- normalize + store ----
#pragma unroll
  for (int m = 0; m < 2; m++)
#pragma unroll
    for (int d = 0; d < 4; d++)
#pragma unroll
      for (int r = 0; r < 4; r++) {
        int qg = q0 + w * 32 + m * 16 + lq * 4 + r;
        int col = h * 64 + d * 16 + l15;
        attb[(rowbase + qg) * 1024 + col] = f2b(oacc[m][d][r] / lrow[m][r]);
      }
}

extern "C" void kernel_launch(void* const* d_in, const int* in_sizes, int n_in,
                              void* d_out, int out_size, void* d_ws, size_t ws_size,
                              hipStream_t stream) {
  const float* x = (const float*)d_in[0];
  const float* wqkv = (const float*)d_in[1];
  const float* wproj = (const float*)d_in[2];
  const float* bproj = (const float*)d_in[3];
  float* out = (float*)d_out;

  unsigned short* xb = (unsigned short*)d_ws;            // 8192*1024
  unsigned short* wqkvb = xb + (size_t)8192 * 1024;      // 3072*1024
  unsigned short* wprojb = wqkvb + (size_t)3072 * 1024;  // 1024*1024
  unsigned short* qkb = wprojb + (size_t)1024 * 1024;    // 8192*2048
  unsigned short* vtb = qkb + (size_t)8192 * 2048;       // 4*16*64*2048
  unsigned short* attb = vtb + (size_t)4 * 16 * 64 * 2048;  // 8192*1024

  cvt_kernel<<<(8192 * 1024 / 4 + 255) / 256, 256, 0, stream>>>(x, xb, 8192 * 1024 / 4);
  cvt_kernel<<<(3072 * 1024 / 4 + 255) / 256, 256, 0, stream>>>(wqkv, wqkvb, 3072 * 1024 / 4);
  cvt_kernel<<<(1024 * 1024 / 4 + 255) / 256, 256, 0, stream>>>(wproj, wprojb, 1024 * 1024 / 4);

  gemm_bt<8192, 3072, 1024, 1>
      <<<dim3(3072 / 128, 8192 / 128), 256, 0, stream>>>(xb, wqkvb, nullptr, qkb, vtb);

  attn_kernel<<<4 * 16 * 16, 256, 0, stream>>>(qkb, vtb, attb);

  gemm_bt<8192, 1024, 1024, 2>
      <<<dim3(1024 / 128, 8192 / 128), 256, 0, stream>>>(attb, wprojb, bproj, out, nullptr);
}

// Round 5
// 369.599 us; speedup vs baseline: 1.3727x; 1.0750x over previous
//
#include <hip/hip_runtime.h>
#include <stdint.h>

// B=4, T=2048, C=1024, H=16, HD=64
// qkb: [B*T][2048] bf16 (Q cols 0..1023, K cols 1024..2047)
// vt : [B][H][64][2048] bf16 (V transposed per head)
// attb: [B*T][1024] bf16

typedef float f32x4 __attribute__((ext_vector_type(4)));
typedef short s16x8 __attribute__((ext_vector_type(8)));
typedef unsigned short u16x4 __attribute__((ext_vector_type(4)));

typedef __attribute__((address_space(1))) const unsigned int gu32;
typedef __attribute__((address_space(3))) unsigned int lu32;

__device__ __forceinline__ unsigned short f2b(float f) {
  unsigned u = __builtin_bit_cast(unsigned, f);
  u += 0x7fffu + ((u >> 16) & 1u);
  return (unsigned short)(u >> 16);
}

__device__ __forceinline__ void gload16(const void* g, void* l) {
  __builtin_amdgcn_global_load_lds((gu32*)g, (lu32*)l, 16, 0, 0);
}

// ---------------- fp32 -> bf16 conversion ----------------
__global__ __launch_bounds__(256) void cvt_kernel(const float* __restrict__ in,
                                                  unsigned short* __restrict__ out,
                                                  int n4) {
  int i = blockIdx.x * 256 + threadIdx.x;
  if (i < n4) {
    float4 v = reinterpret_cast<const float4*>(in)[i];
    ushort4 o;
    o.x = f2b(v.x); o.y = f2b(v.y); o.z = f2b(v.z); o.w = f2b(v.w);
    reinterpret_cast<ushort4*>(out)[i] = o;
  }
}

// ---------------- GEMM: C = A[M][K] * B[N][K]^T ----------------
// OUTMODE 1: QKV split: cols<2048 -> qkb (C0, [M][2048]); cols>=2048 -> vt (C1, [B][H][64][2048])
// OUTMODE 2: f32 + bias -> C0
template <int M, int N, int K, int OUTMODE>
__global__ __launch_bounds__(256) void gemm_bt(const unsigned short* __restrict__ A,
                                               const unsigned short* __restrict__ B,
                                               const float* __restrict__ bias,
                                               void* __restrict__ C0,
                                               void* __restrict__ C1) {
  __shared__ __align__(16) unsigned short As[128 * 64];
  __shared__ __align__(16) unsigned short Bs[128 * 64];
  const int tid = threadIdx.x;
  const int l = tid & 63, w = tid >> 6;
  const int l15 = l & 15, lq = l >> 4;
  const int wr = w >> 1, wc = w & 1;
  const int m0 = blockIdx.y * 128, n0 = blockIdx.x * 128;
  f32x4 acc[4][4] = {};
  for (int k0 = 0; k0 < K; k0 += 64) {
    __syncthreads();
#pragma unroll
    for (int i = 0; i < 4; i++) {
      int idx = i * 256 + tid;
      gload16(A + (size_t)(m0 + (idx >> 3)) * K + k0 + (idx & 7) * 8, &As[idx * 8]);
    }
#pragma unroll
    for (int i = 0; i < 4; i++) {
      int idx = i * 256 + tid;
      gload16(B + (size_t)(n0 + (idx >> 3)) * K + k0 + (idx & 7) * 8, &Bs[idx * 8]);
    }
    __syncthreads();
#pragma unroll
    for (int kk = 0; kk < 2; kk++) {
      s16x8 af[4], bfv[4];
#pragma unroll
      for (int m = 0; m < 4; m++)
        af[m] = *(const s16x8*)&As[(wr * 64 + m * 16 + l15) * 64 + kk * 32 + lq * 8];
#pragma unroll
      for (int n = 0; n < 4; n++)
        bfv[n] = *(const s16x8*)&Bs[(wc * 64 + n * 16 + l15) * 64 + kk * 32 + lq * 8];
#pragma unroll
      for (int m = 0; m < 4; m++)
#pragma unroll
        for (int n = 0; n < 4; n++)
          acc[m][n] = __builtin_amdgcn_mfma_f32_16x16x32_bf16(af[m], bfv[n], acc[m][n], 0, 0, 0);
    }
  }
  if (OUTMODE == 1 && n0 >= 2048) {
    // V columns: write transposed into vt[b][h][d][q], pack 4 q (r=0..3) per store
    unsigned short* vt = (unsigned short*)C1;
#pragma unroll
    for (int m = 0; m < 4; m++)
#pragma unroll
      for (int n = 0; n < 4; n++) {
        int row0 = m0 + wr * 64 + m * 16 + lq * 4;  // q base (mult of 4)
        int vcol = n0 - 2048 + wc * 64 + n * 16 + l15;  // h*64+d
        int bb = row0 >> 11, q = row0 & 2047;
        u16x4 o;
#pragma unroll
        for (int r = 0; r < 4; r++) o[r] = f2b(acc[m][n][r]);
        *(u16x4*)&vt[((size_t)(bb * 16 + (vcol >> 6)) * 64 + (vcol & 63)) * 2048 + q] = o;
      }
  } else {
#pragma unroll
    for (int m = 0; m < 4; m++)
#pragma unroll
      for (int n = 0; n < 4; n++)
#pragma unroll
        for (int r = 0; r < 4; r++) {
          int row = m0 + wr * 64 + m * 16 + lq * 4 + r;
          int col = n0 + wc * 64 + n * 16 + l15;
          float v = acc[m][n][r];
          if (OUTMODE == 2) {
            ((float*)C0)[(size_t)row * N + col] = v + bias[col];
          } else if (OUTMODE == 1) {
            ((unsigned short*)C0)[(size_t)row * 2048 + col] = f2b(v);
          } else {
            ((unsigned short*)C0)[(size_t)row * N + col] = f2b(v);
          }
        }
  }
}

// ---------------- Flash attention (causal), load-balanced pairs ----------------
// 1 block = (b, h, pair pi): processes q-blocks qbA=15-pi then qbB=pi (128 rows each).
// Every block does 34 KV tiles -> uniform duration, no tail.
// 4 waves x 32 q rows; KV tiles of 64, double-buffered; XOR-swizzle byte^=((row&7)<<4).
__global__ __launch_bounds__(256) void attn_kernel(const unsigned short* __restrict__ qkb,
                                                   const unsigned short* __restrict__ vt,
                                                   unsigned short* __restrict__ attb) {
  __shared__ __align__(16) unsigned short Kb[2][64 * 64];
  __shared__ __align__(16) unsigned short Vb[2][64 * 64];
  __shared__ __align__(16) unsigned short Pl[4][32 * 64];
  const int tid = threadIdx.x, l = tid & 63, w = tid >> 6;
  const int l15 = l & 15, lq = l >> 4;
  const int bid = blockIdx.x;
  const int pi = bid & 7;
  const int h = (bid >> 3) & 15, b = bid >> 7;
  const size_t rowbase = (size_t)b * 2048;
  const unsigned short* kbase = qkb + rowbase * 2048 + 1024 + h * 64;
  const unsigned short* vbase = vt + (size_t)(b * 16 + h) * 64 * 2048;
  const int swz = (l15 & 7) << 4;            // read-side XOR (byte units)
  const float c = 0.18033688011112042f;      // 0.125 * log2(e)

  auto stage = [&](int bs, int t) {
    const int kv0 = t << 6;
#pragma unroll
    for (int i = 0; i < 2; i++) {
      int idx = i * 256 + tid;
      int row = idx >> 3, colb = (idx & 7) << 4;
      int src = colb ^ ((row & 7) << 4);
      gload16(kbase + (size_t)(kv0 + row) * 2048 + (src >> 1), &Kb[bs][idx * 8]);
    }
#pragma unroll
    for (int i = 0; i < 2; i++) {
      int idx = i * 256 + tid;
      int row = idx >> 3, colb = (idx & 7) << 4;
      int src = colb ^ ((row & 7) << 4);
      gload16(vbase + (size_t)row * 2048 + kv0 + (src >> 1), &Vb[bs][idx * 8]);
    }
  };

  for (int half = 0; half < 2; half++) {
    const int qb = half ? pi : 15 - pi;
    const int q0 = qb * 128;
    const int nt = 2 * qb + 2;
    const int qwmin = q0 + w * 32;

    // Q fragments in registers: qf[m][kk], row = q0+w*32+m*16+l15, k = kk*32+lq*8+j
    s16x8 qf[2][2];
#pragma unroll
    for (int m = 0; m < 2; m++)
#pragma unroll
      for (int kk = 0; kk < 2; kk++)
        qf[m][kk] = *(const s16x8*)&qkb[(rowbase + q0 + w * 32 + m * 16 + l15) * 2048 +
                                        h * 64 + kk * 32 + lq * 8];

    f32x4 oacc[2][4] = {};
    float mrow[2][4], lrow[2][4];
#pragma unroll
    for (int m = 0; m < 2; m++)
#pragma unroll
      for (int r = 0; r < 4; r++) { mrow[m][r] = -1e30f; lrow[m][r] = 0.f; }

    stage(0, 0);  // previous half's final barrier makes this safe
    __syncthreads();
    int cur = 0;
    for (int t = 0; t < nt; ++t) {
      const int kv0 = t << 6;
      if (t + 1 < nt) stage(cur ^ 1, t + 1);
      if (kv0 <= qwmin + 31) {  // wave has at least one unmasked row
        // ---- S = Q K^T (32 x 64 per wave), raw (unscaled) scores ----
        f32x4 s[2][4];
#pragma unroll
        for (int m = 0; m < 2; m++)
#pragma unroll
          for (int n = 0; n < 4; n++) s[m][n] = (f32x4){0.f, 0.f, 0.f, 0.f};
#pragma unroll
        for (int kk = 0; kk < 2; kk++) {
          s16x8 bk[4];
#pragma unroll
          for (int n = 0; n < 4; n++)
            bk[n] = *(const s16x8*)&Kb[cur][(n * 16 + l15) * 64 +
                                            (((kk * 64 + lq * 16) ^ swz) >> 1)];
#pragma unroll
          for (int m = 0; m < 2; m++)
#pragma unroll
            for (int n = 0; n < 4; n++)
              s[m][n] = __builtin_amdgcn_mfma_f32_16x16x32_bf16(qf[m][kk], bk[n], s[m][n], 0, 0, 0);
        }
        // ---- mask + online softmax in raw domain (scale fused into exp2) ----
        const bool needmask = (kv0 + 63) > qwmin;
#pragma unroll
        for (int m = 0; m < 2; m++)
#pragma unroll
          for (int r = 0; r < 4; r++) {
            const int qg = qwmin + m * 16 + lq * 4 + r;
            float mx = -1e30f;
#pragma unroll
            for (int n = 0; n < 4; n++) {
              float v = s[m][n][r];
              if (needmask) v = (kv0 + n * 16 + l15 <= qg) ? v : -1e30f;
              s[m][n][r] = v;
              mx = fmaxf(mx, v);
            }
            mx = fmaxf(mx, __shfl_xor(mx, 1));
            mx = fmaxf(mx, __shfl_xor(mx, 2));
            mx = fmaxf(mx, __shfl_xor(mx, 4));
            mx = fmaxf(mx, __shfl_xor(mx, 8));
            float mn = fmaxf(mrow[m][r], mx);
            float alpha = exp2f((mrow[m][r] - mn) * c);
            mrow[m][r] = mn;
            float mc = mn * c;
            float ssum = 0.f;
#pragma unroll
            for (int n = 0; n < 4; n++) {
              float p = exp2f(fmaf(s[m][n][r], c, -mc));
              s[m][n][r] = p;
              ssum += p;
            }
            ssum += __shfl_xor(ssum, 1);
            ssum += __shfl_xor(ssum, 2);
            ssum += __shfl_xor(ssum, 4);
            ssum += __shfl_xor(ssum, 8);
            lrow[m][r] = lrow[m][r] * alpha + ssum;
#pragma unroll
            for (int d = 0; d < 4; d++) oacc[m][d][r] *= alpha;
          }
        // ---- P -> LDS bf16 (swizzled) ----
#pragma unroll
        for (int m = 0; m < 2; m++)
#pragma unroll
          for (int r = 0; r < 4; r++) {
            int row = m * 16 + lq * 4 + r;
            int rx = (row & 7) << 4;
#pragma unroll
            for (int n = 0; n < 4; n++)
              Pl[w][row * 64 + ((((n * 16 + l15) * 2) ^ rx) >> 1)] = f2b(s[m][n][r]);
          }
        // ---- O += P V ----
        s16x8 ap[2][2];
#pragma unroll
        for (int m = 0; m < 2; m++)
#pragma unroll
          for (int kk = 0; kk < 2; kk++)
            ap[m][kk] = *(const s16x8*)&Pl[w][(m * 16 + l15) * 64 +
                                              (((kk * 64 + lq * 16) ^ swz) >> 1)];
#pragma unroll
        for (int kk = 0; kk < 2; kk++) {
          s16x8 bv[4];
#pragma unroll
          for (int d = 0; d < 4; d++)
            bv[d] = *(const s16x8*)&Vb[cur][(d * 16 + l15) * 64 +
                                            (((kk * 64 + lq * 16) ^ swz) >> 1)];
#pragma unroll
          for (int m = 0; m < 2; m++)
#pragma unroll
            for (int d = 0; d < 4; d++)
              oacc[m][d] = __builtin_amdgcn_mfma_f32_16x16x32_bf16(ap[m][kk], bv[d], oacc[m][d], 0, 0, 0);
        }
      }
      __syncthreads();
      cur ^= 1;
    }

    // ---- normalize + store (registers only; next half's stage may overlap) ----
#pragma unroll
    for (int m = 0; m < 2; m++)
#pragma unroll
      for (int d = 0; d < 4; d++) {
        f32x4 o4;
#pragma unroll
        for (int r = 0; r < 4; r++) o4[r] = oacc[m][d][r] / lrow[m][r];
#pragma unroll
        for (int r = 0; r < 4; r++) {
          int qg = q0 + w * 32 + m * 16 + lq * 4 + r;
          attb[(rowbase + qg) * 1024 + h * 64 + d * 16 + l15] = f2b(o4[r]);
        }
      }
  }
}

extern "C" void kernel_launch(void* const* d_in, const int* in_sizes, int n_in,
                              void* d_out, int out_size, void* d_ws, size_t ws_size,
                              hipStream_t stream) {
  const float* x = (const float*)d_in[0];
  const float* wqkv = (const float*)d_in[1];
  const float* wproj = (const float*)d_in[2];
  const float* bproj = (const float*)d_in[3];
  float* out = (float*)d_out;

  unsigned short* xb = (unsigned short*)d_ws;            // 8192*1024
  unsigned short* wqkvb = xb + (size_t)8192 * 1024;      // 3072*1024
  unsigned short* wprojb = wqkvb + (size_t)3072 * 1024;  // 1024*1024
  unsigned short* qkb = wprojb + (size_t)1024 * 1024;    // 8192*2048
  unsigned short* vtb = qkb + (size_t)8192 * 2048;       // 4*16*64*2048
  unsigned short* attb = vtb + (size_t)4 * 16 * 64 * 2048;  // 8192*1024

  cvt_kernel<<<(8192 * 1024 / 4 + 255) / 256, 256, 0, stream>>>(x, xb, 8192 * 1024 / 4);
  cvt_kernel<<<(3072 * 1024 / 4 + 255) / 256, 256, 0, stream>>>(wqkv, wqkvb, 3072 * 1024 / 4);
  cvt_kernel<<<(1024 * 1024 / 4 + 255) / 256, 256, 0, stream>>>(wproj, wprojb, 1024 * 1024 / 4);

  gemm_bt<8192, 3072, 1024, 1>
      <<<dim3(3072 / 128, 8192 / 128), 256, 0, stream>>>(xb, wqkvb, nullptr, qkb, vtb);

  attn_kernel<<<4 * 16 * 8, 256, 0, stream>>>(qkb, vtb, attb);

  gemm_bt<8192, 1024, 1024, 2>
      <<<dim3(1024 / 128, 8192 / 128), 256, 0, stream>>>(attb, wprojb, bproj, out, nullptr);
}